// Round 6
// baseline (454.640 us; speedup 1.0000x reference)
//
#include <hip/hip_runtime.h>

#define NKK 8192
#define NQQ 8192
#define DDIM 64

typedef __attribute__((ext_vector_type(8))) short short8;
typedef __attribute__((ext_vector_type(4))) float f32x4;
typedef __attribute__((ext_vector_type(2))) unsigned int u32x2;

static __device__ __forceinline__ unsigned short f2b(float x) {
  unsigned int u = __builtin_bit_cast(unsigned int, x);
  unsigned int r = (u + 0x7fffu + ((u >> 16) & 1u)) >> 16;  // RTNE
  return (unsigned short)r;
}
static __device__ __forceinline__ unsigned int pk2(float a, float b) {
  return (unsigned int)f2b(a) | ((unsigned int)f2b(b) << 16);
}

// ---------------- pre-convert: Q,K -> bf16 row-major ; V -> bf16 transposed [64][8192]
__global__ __launch_bounds__(256) void prep_kernel(
    const float* __restrict__ K, const float* __restrict__ V, const float* __restrict__ Q,
    unsigned short* __restrict__ Kb, unsigned short* __restrict__ Qb, unsigned short* __restrict__ Vtb) {
  __shared__ unsigned short vt[64][72];
  const int b = blockIdx.x, t = threadIdx.x;
  const size_t base = (size_t)b * 4096;
#pragma unroll
  for (int i = 0; i < 4; ++i) {
    size_t idx = base + (size_t)i * 1024 + (size_t)t * 4;
    float4 kv = *(const float4*)(K + idx);
    float4 qv = *(const float4*)(Q + idx);
    ushort4 ko, qo;
    ko.x = f2b(kv.x); ko.y = f2b(kv.y); ko.z = f2b(kv.z); ko.w = f2b(kv.w);
    qo.x = f2b(qv.x); qo.y = f2b(qv.y); qo.z = f2b(qv.z); qo.w = f2b(qv.w);
    *(ushort4*)(Kb + idx) = ko;
    *(ushort4*)(Qb + idx) = qo;
  }
  const int r0 = b * 64;
#pragma unroll
  for (int i = 0; i < 4; ++i) {
    int kl = (t >> 4) + i * 16;
    int c4 = (t & 15) * 4;
    float4 v = *(const float4*)(V + (size_t)(r0 + kl) * 64 + c4);
    vt[c4 + 0][kl] = f2b(v.x);
    vt[c4 + 1][kl] = f2b(v.y);
    vt[c4 + 2][kl] = f2b(v.z);
    vt[c4 + 3][kl] = f2b(v.w);
  }
  __syncthreads();
  {
    int d = t >> 2, kc = (t & 3) * 16;
    uint4 a0 = *(const uint4*)(&vt[d][kc]);
    uint4 a1 = *(const uint4*)(&vt[d][kc + 8]);
    *(uint4*)(Vtb + (size_t)d * NKK + r0 + kc) = a0;
    *(uint4*)(Vtb + (size_t)d * NKK + r0 + kc + 8) = a1;
  }
}

// ---------------- main fused attention (S^T orientation: float4 m loads)
// Each block: 16 q-rows, 8 waves k-interleaved over 8192 keys (32 tiles x 32 keys per wave).
__global__ __launch_bounds__(512, 4) void attn_kernel(
    const float* __restrict__ mg, const unsigned short* __restrict__ Kb,
    const unsigned short* __restrict__ Qb, const unsigned short* __restrict__ Vtb,
    float* __restrict__ out) {
  __shared__ unsigned short Pl[8][16][40];   // per-wave P tile [q][k], stride 40 bf16 (80 B)
  __shared__ float accslot[4][4][4][64];     // 16 KB combine slots
  __shared__ float lslot[4][64];

  const int tid = threadIdx.x;
  const int wid = tid >> 6;
  const int lane = tid & 63;
  const int c = lane & 15;   // lane col: q-row within block / A-frag row
  const int g = lane >> 4;   // lane group 0..3
  const int q0 = blockIdx.x * 16;

  const float LOG2E = 1.4426950408889634f;
  const float C1 = 0.125f * LOG2E;   // 1/sqrt(64) * log2(e)
  const float MM = -8.0f * LOG2E;    // static max shift M0 = 8

  // Q fragments (B operand of S^T MFMA): qf[dh] = Q[q0+c][dh*32+8g .. +7]
  short8 qf[2];
#pragma unroll
  for (int dh = 0; dh < 2; ++dh)
    qf[dh] = __builtin_bit_cast(
        short8, *(const uint4*)(Qb + (size_t)(q0 + c) * 64 + dh * 32 + 8 * g));

  f32x4 acc[4];
#pragma unroll
  for (int dt = 0; dt < 4; ++dt) acc[dt] = f32x4{0.f, 0.f, 0.f, 0.f};
  float lsum = 0.f;

  const float* mrow = mg + (size_t)(q0 + c) * NKK + 4 * g;

  f32x4 mA[2], mB[2];

  auto loadM = [&](int t, f32x4 (&mb)[2]) {
    const float* p = mrow + (unsigned)((wid + 8 * t) * 32);
    mb[0] = *(const f32x4*)(p);
    mb[1] = *(const f32x4*)(p + 16);
  };

  auto computeTile = [&](int t, const f32x4 (&mb)[2]) {
    const int k0 = (wid + 8 * t) * 32;
    short8 kf[4];
#pragma unroll
    for (int kb = 0; kb < 2; ++kb)
#pragma unroll
      for (int dh = 0; dh < 2; ++dh)
        kf[kb * 2 + dh] = __builtin_bit_cast(
            short8, *(const uint4*)(Kb + (size_t)(k0 + kb * 16 + c) * 64 + dh * 32 + 8 * g));
    short8 vf[4];
#pragma unroll
    for (int dt = 0; dt < 4; ++dt)
      vf[dt] = __builtin_bit_cast(
          short8, *(const uint4*)(Vtb + (size_t)(dt * 16 + c) * NKK + k0 + 8 * g));

#pragma unroll
    for (int kb = 0; kb < 2; ++kb) {
      f32x4 z = f32x4{0.f, 0.f, 0.f, 0.f};
      z = __builtin_amdgcn_mfma_f32_16x16x32_bf16(kf[kb * 2 + 0], qf[0], z, 0, 0, 0);
      z = __builtin_amdgcn_mfma_f32_16x16x32_bf16(kf[kb * 2 + 1], qf[1], z, 0, 0, 0);
      // lane holds S^T[k = k0+kb*16+4g+i][q = q0+c]; m fragment is a float4 of consecutive k
      float p[4];
#pragma unroll
      for (int i = 0; i < 4; ++i) {
        float e = __builtin_fmaf(z[i], C1, __builtin_fmaf(mb[kb][i], LOG2E, MM));
        p[i] = __builtin_amdgcn_exp2f(e);
        lsum += p[i];
      }
      u32x2 w;
      w[0] = pk2(p[0], p[1]);
      w[1] = pk2(p[2], p[3]);
      *(u32x2*)(&Pl[wid][c][kb * 16 + 4 * g]) = w;   // P[q=c][k=kb*16+4g..+3]
    }
    // A-fragment for PV: P[q=c][8g..8g+7] (16 B aligned, stride 80 B)
    short8 pa = __builtin_bit_cast(short8, *(const uint4*)(&Pl[wid][c][8 * g]));
#pragma unroll
    for (int dt = 0; dt < 4; ++dt)
      acc[dt] = __builtin_amdgcn_mfma_f32_16x16x32_bf16(pa, vf[dt], acc[dt], 0, 0, 0);
  };

  loadM(0, mA);
  loadM(1, mB);
  for (int t = 0; t < 32; t += 2) {
    computeTile(t, mA);
    if (t + 2 < 32) loadM(t + 2, mA);
    computeTile(t + 1, mB);
    if (t + 3 < 32) loadM(t + 3, mB);
  }

  // reduce lsum over lane groups g (k lives in lane bits 4,5 + in-lane)
  lsum += __shfl_xor(lsum, 16);
  lsum += __shfl_xor(lsum, 32);
  // now every lane holds this wave's partial row-sum for q = c

  auto writeSlot = [&](int slot) {
#pragma unroll
    for (int dt = 0; dt < 4; ++dt)
#pragma unroll
      for (int i = 0; i < 4; ++i) accslot[slot][dt][i][lane] = acc[dt][i];
    lslot[slot][lane] = lsum;
  };
  auto addSlot = [&](int slot) {
#pragma unroll
    for (int dt = 0; dt < 4; ++dt)
#pragma unroll
      for (int i = 0; i < 4; ++i) acc[dt][i] += accslot[slot][dt][i][lane];
    lsum += lslot[slot][lane];
  };

  // 8 -> 4 -> 2 -> 1 tree combine of k-slice partials (plain sums)
  if (wid >= 4) writeSlot(wid - 4);
  __syncthreads();
  if (wid < 4) addSlot(wid);
  __syncthreads();
  if (wid == 2 || wid == 3) writeSlot(wid - 2);
  __syncthreads();
  if (wid < 2) addSlot(wid);
  __syncthreads();
  if (wid == 1) writeSlot(0);
  __syncthreads();
  if (wid == 0) {
    addSlot(0);
    // O C-layout: lane holds O[q=4g+i][d=16dt+c]; row-sum for q lives on lane q (c'=q)
#pragma unroll
    for (int i = 0; i < 4; ++i) {
      float rs = __shfl(lsum, 4 * g + i);
      float rl = 1.0f / rs;
      const int q = q0 + 4 * g + i;
#pragma unroll
      for (int dt = 0; dt < 4; ++dt)
        out[(size_t)q * 64 + dt * 16 + c] = acc[dt][i] * rl;
    }
  }
}

extern "C" void kernel_launch(void* const* d_in, const int* in_sizes, int n_in,
                              void* d_out, int out_size, void* d_ws, size_t ws_size,
                              hipStream_t stream) {
  (void)in_sizes; (void)n_in; (void)out_size; (void)ws_size;
  const float* K = (const float*)d_in[0];
  const float* V = (const float*)d_in[1];
  const float* Q = (const float*)d_in[2];
  const float* mg = (const float*)d_in[3];
  float* out = (float*)d_out;

  unsigned short* Kb = (unsigned short*)d_ws;
  unsigned short* Qb = Kb + (size_t)NKK * DDIM;
  unsigned short* Vtb = Qb + (size_t)NQQ * DDIM;

  prep_kernel<<<128, 256, 0, stream>>>(K, V, Q, Kb, Qb, Vtb);
  attn_kernel<<<512, 512, 0, stream>>>(mg, Kb, Qb, Vtb, out);
}

// Round 9
// 413.397 us; speedup vs baseline: 1.0998x; 1.0998x over previous
//
#include <hip/hip_runtime.h>

#define NKK 8192
#define NQQ 8192
#define DDIM 64

typedef __attribute__((ext_vector_type(8))) short short8;
typedef __attribute__((ext_vector_type(4))) float f32x4;
typedef __attribute__((ext_vector_type(2))) unsigned int u32x2;

static __device__ __forceinline__ unsigned short f2b(float x) {
  unsigned int u = __builtin_bit_cast(unsigned int, x);
  unsigned int r = (u + 0x7fffu + ((u >> 16) & 1u)) >> 16;  // RTNE
  return (unsigned short)r;
}
static __device__ __forceinline__ unsigned int pk2(float a, float b) {
  return (unsigned int)f2b(a) | ((unsigned int)f2b(b) << 16);
}

// ---------------- pre-convert: Q,K -> bf16 row-major ; V -> bf16 transposed [64][8192]
__global__ __launch_bounds__(256) void prep_kernel(
    const float* __restrict__ K, const float* __restrict__ V, const float* __restrict__ Q,
    unsigned short* __restrict__ Kb, unsigned short* __restrict__ Qb, unsigned short* __restrict__ Vtb) {
  __shared__ unsigned short vt[64][72];
  const int b = blockIdx.x, t = threadIdx.x;
  const size_t base = (size_t)b * 4096;
#pragma unroll
  for (int i = 0; i < 4; ++i) {
    size_t idx = base + (size_t)i * 1024 + (size_t)t * 4;
    float4 kv = *(const float4*)(K + idx);
    float4 qv = *(const float4*)(Q + idx);
    ushort4 ko, qo;
    ko.x = f2b(kv.x); ko.y = f2b(kv.y); ko.z = f2b(kv.z); ko.w = f2b(kv.w);
    qo.x = f2b(qv.x); qo.y = f2b(qv.y); qo.z = f2b(qv.z); qo.w = f2b(qv.w);
    *(ushort4*)(Kb + idx) = ko;
    *(ushort4*)(Qb + idx) = qo;
  }
  const int r0 = b * 64;
#pragma unroll
  for (int i = 0; i < 4; ++i) {
    int kl = (t >> 4) + i * 16;
    int c4 = (t & 15) * 4;
    float4 v = *(const float4*)(V + (size_t)(r0 + kl) * 64 + c4);
    vt[c4 + 0][kl] = f2b(v.x);
    vt[c4 + 1][kl] = f2b(v.y);
    vt[c4 + 2][kl] = f2b(v.z);
    vt[c4 + 3][kl] = f2b(v.w);
  }
  __syncthreads();
  {
    int d = t >> 2, kc = (t & 3) * 16;
    uint4 a0 = *(const uint4*)(&vt[d][kc]);
    uint4 a1 = *(const uint4*)(&vt[d][kc + 8]);
    *(uint4*)(Vtb + (size_t)d * NKK + r0 + kc) = a0;
    *(uint4*)(Vtb + (size_t)d * NKK + r0 + kc + 8) = a1;
  }
}

// ---------------- main fused attention
// 512 threads / 8 waves per block, 16 q-rows per block, 512 blocks.
// Per step: block covers contiguous 256-key chunk (wave w -> keys [t*256+w*32, +32)).
// m staged into LDS via global_load_lds, double-buffered one step ahead (T3/T4 2-phase).
__global__ __launch_bounds__(512, 4) void attn_kernel(
    const float* __restrict__ mg, const unsigned short* __restrict__ Kb,
    const unsigned short* __restrict__ Qb, const unsigned short* __restrict__ Vtb,
    float* __restrict__ out) {
  // [0,32768):  m staging, 2 x [16 rows][256 f32] (16B-XOR swizzled)  UNION post-loop combine slots
  // [32768,43008): P tiles, 8 waves x [16][40] bf16
  __shared__ __align__(16) char smem[43008];

  const int tid = threadIdx.x;
  const int wid = tid >> 6;
  const int lane = tid & 63;
  const int c = lane & 15;   // q-row within block
  const int g = lane >> 4;   // lane group 0..3
  const int q0 = blockIdx.x * 16;

  const float LOG2E = 1.4426950408889634f;
  const float C1 = 0.125f * LOG2E;   // 1/sqrt(64) * log2(e)
  const float MM = -8.0f * LOG2E;    // static max shift M0 = 8

  // Q fragments (B operand of S^T MFMA)
  short8 qf[2];
#pragma unroll
  for (int dh = 0; dh < 2; ++dh)
    qf[dh] = __builtin_bit_cast(
        short8, *(const uint4*)(Qb + (size_t)(q0 + c) * 64 + dh * 32 + 8 * g));

  f32x4 acc[4];
#pragma unroll
  for (int dt = 0; dt < 4; ++dt) acc[dt] = f32x4{0.f, 0.f, 0.f, 0.f};
  float lsum = 0.f;

  unsigned short* Pw = (unsigned short*)(smem + 32768) + wid * 640;  // [16][40]
  const unsigned short* Pr = Pw + c * 40 + 8 * g;

  // ---- m staging: lane-linear LDS dest, inverse-swizzled global source (rule #21)
  auto stageM = [&](int t, int buf) {
    const unsigned o = (unsigned)tid * 16u;
#pragma unroll
    for (int h = 0; h < 2; ++h) {
      unsigned oo = o + (unsigned)h * 8192u;
      unsigned row = oo >> 10;
      unsigned cb = (oo & 1023u) ^ ((row & 7u) << 4);
      const float* src = mg + (size_t)(q0 + (int)row) * NKK + (unsigned)t * 256u + (cb >> 2);
      char* dst = smem + buf * 16384 + oo;
      __builtin_amdgcn_global_load_lds(
          (const __attribute__((address_space(1))) void*)src,
          (__attribute__((address_space(3))) void*)dst, 16, 0, 0);
    }
  };

  // prologue: stage step 0
  stageM(0, 0);
  __syncthreads();

  const unsigned sw = ((unsigned)(c & 7)) << 4;

  for (int t = 0; t < 32; ++t) {
    const int cur = t & 1;
    const int k0 = t * 256 + wid * 32;

    // (1) K/V register loads for this step — issued FIRST so their vmcnt waits
    //     do not drain the async m-stage (FIFO ordering).
    short8 kf[4], vf[4];
#pragma unroll
    for (int kb = 0; kb < 2; ++kb)
#pragma unroll
      for (int dh = 0; dh < 2; ++dh)
        kf[kb * 2 + dh] = __builtin_bit_cast(
            short8, *(const uint4*)(Kb + (size_t)(k0 + kb * 16 + c) * 64 + dh * 32 + 8 * g));
#pragma unroll
    for (int dt = 0; dt < 4; ++dt)
      vf[dt] = __builtin_bit_cast(
          short8, *(const uint4*)(Vtb + (size_t)(dt * 16 + c) * NKK + k0 + 8 * g));
    __builtin_amdgcn_sched_barrier(0);

    // (2) async-stage m for step t+1 into the other buffer
    if (t + 1 < 32) stageM(t + 1, cur ^ 1);
    __builtin_amdgcn_sched_barrier(0);

    // (3) m fragments from LDS (swizzled read)
    const char* mrow = smem + cur * 16384 + c * 1024;
    f32x4 mb[2];
    mb[0] = *(const f32x4*)(mrow + (((unsigned)(wid * 128 + g * 16)) ^ sw));
    mb[1] = *(const f32x4*)(mrow + (((unsigned)(wid * 128 + g * 16 + 64)) ^ sw));

    // (4) S^T = K·Q^T, softmax numerator, P->LDS, PV
#pragma unroll
    for (int kb = 0; kb < 2; ++kb) {
      f32x4 z = f32x4{0.f, 0.f, 0.f, 0.f};
      z = __builtin_amdgcn_mfma_f32_16x16x32_bf16(kf[kb * 2 + 0], qf[0], z, 0, 0, 0);
      z = __builtin_amdgcn_mfma_f32_16x16x32_bf16(kf[kb * 2 + 1], qf[1], z, 0, 0, 0);
      float p[4];
#pragma unroll
      for (int i = 0; i < 4; ++i) {
        float e = __builtin_fmaf(z[i], C1, __builtin_fmaf(mb[kb][i], LOG2E, MM));
        p[i] = __builtin_amdgcn_exp2f(e);
        lsum += p[i];
      }
      u32x2 w;
      w[0] = pk2(p[0], p[1]);
      w[1] = pk2(p[2], p[3]);
      *(u32x2*)(Pw + c * 40 + kb * 16 + 4 * g) = w;  // P[q=c][k=kb*16+4g..+3]
    }
    short8 pa = __builtin_bit_cast(short8, *(const uint4*)(Pr));
#pragma unroll
    for (int dt = 0; dt < 4; ++dt)
      acc[dt] = __builtin_amdgcn_mfma_f32_16x16x32_bf16(pa, vf[dt], acc[dt], 0, 0, 0);

    // (5) single drain+barrier per step: completes the t+1 m-stage for all waves
    __syncthreads();
  }

  // reduce lsum over lane groups (k lives in lane bits 4,5 + in-lane)
  lsum += __shfl_xor(lsum, 16);
  lsum += __shfl_xor(lsum, 32);

  // ---- k-slice combine (8->4->2->1), slots alias the m staging buffer (loop is done)
  float* accs = (float*)smem;            // [4 slots][16][64] f32
  float* lsl = (float*)(smem + 16384);   // [4 slots][64]

  auto writeSlot = [&](int slot) {
    float* s = accs + slot * 1024;
#pragma unroll
    for (int dt = 0; dt < 4; ++dt)
#pragma unroll
      for (int i = 0; i < 4; ++i) s[(dt * 4 + i) * 64 + lane] = acc[dt][i];
    lsl[slot * 64 + lane] = lsum;
  };
  auto addSlot = [&](int slot) {
    const float* s = accs + slot * 1024;
#pragma unroll
    for (int dt = 0; dt < 4; ++dt)
#pragma unroll
      for (int i = 0; i < 4; ++i) acc[dt][i] += s[(dt * 4 + i) * 64 + lane];
    lsum += lsl[slot * 64 + lane];
  };

  if (wid >= 4) writeSlot(wid - 4);
  __syncthreads();
  if (wid < 4) addSlot(wid);
  __syncthreads();
  if (wid == 2 || wid == 3) writeSlot(wid - 2);
  __syncthreads();
  if (wid < 2) addSlot(wid);
  __syncthreads();
  if (wid == 1) writeSlot(0);
  __syncthreads();
  if (wid == 0) {
    addSlot(0);
    // O C-layout: lane holds O[q=4g+i][d=16dt+c]; row-sum for q lives on lane q
#pragma unroll
    for (int i = 0; i < 4; ++i) {
      float rs = __shfl(lsum, 4 * g + i);
      float rl = 1.0f / rs;
      const int q = q0 + 4 * g + i;
#pragma unroll
      for (int dt = 0; dt < 4; ++dt)
        out[(size_t)q * 64 + dt * 16 + c] = acc[dt][i] * rl;
    }
  }
}

extern "C" void kernel_launch(void* const* d_in, const int* in_sizes, int n_in,
                              void* d_out, int out_size, void* d_ws, size_t ws_size,
                              hipStream_t stream) {
  (void)in_sizes; (void)n_in; (void)out_size; (void)ws_size;
  const float* K = (const float*)d_in[0];
  const float* V = (const float*)d_in[1];
  const float* Q = (const float*)d_in[2];
  const float* mg = (const float*)d_in[3];
  float* out = (float*)d_out;

  unsigned short* Kb = (unsigned short*)d_ws;
  unsigned short* Qb = Kb + (size_t)NKK * DDIM;
  unsigned short* Vtb = Qb + (size_t)NQQ * DDIM;

  prep_kernel<<<128, 256, 0, stream>>>(K, V, Q, Kb, Qb, Vtb);
  attn_kernel<<<512, 512, 0, stream>>>(mg, Kb, Qb, Vtb, out);
}